// Round 1
// baseline (317.970 us; speedup 1.0000x reference)
//
#include <hip/hip_runtime.h>
#include <hip/hip_bf16.h>

typedef unsigned short u16;
typedef unsigned int u32;
typedef __bf16 bf16x8 __attribute__((ext_vector_type(8)));
typedef float f32x4 __attribute__((ext_vector_type(4)));

#define N_ROWS 8192
#define DIM 512
#define BM 128
#define BN 128
#define BK 64
#define TEMP_INV (1.0f / 0.07f)

// round-to-nearest-even float -> bf16 bit pattern
__device__ __forceinline__ u16 f2bf(float f) {
    union { float f; u32 u; } a;
    a.f = f;
    u32 r = a.u + 0x7FFFu + ((a.u >> 16) & 1u);
    return (u16)(r >> 16);
}

// ---------------- kernel 1: L2-normalize rows, cast to bf16 ----------------
// one wave per row; 2048 blocks x 256 threads (4 rows/block)
__global__ __launch_bounds__(256) void norm_cast_kernel(
        const float* __restrict__ x, u16* __restrict__ hb) {
    int row  = blockIdx.x * 4 + (threadIdx.x >> 6);
    int lane = threadIdx.x & 63;
    const float4* xr = (const float4*)(x + (size_t)row * DIM);
    float4 v0 = xr[lane * 2 + 0];
    float4 v1 = xr[lane * 2 + 1];
    float ss = v0.x * v0.x + v0.y * v0.y + v0.z * v0.z + v0.w * v0.w
             + v1.x * v1.x + v1.y * v1.y + v1.z * v1.z + v1.w * v1.w;
#pragma unroll
    for (int off = 32; off; off >>= 1) ss += __shfl_xor(ss, off);
    float nrm = fmaxf(sqrtf(ss), 1e-12f);
    float s = 1.0f / nrm;
    uint4 o;
    o.x = (u32)f2bf(v0.x * s) | ((u32)f2bf(v0.y * s) << 16);
    o.y = (u32)f2bf(v0.z * s) | ((u32)f2bf(v0.w * s) << 16);
    o.z = (u32)f2bf(v1.x * s) | ((u32)f2bf(v1.y * s) << 16);
    o.w = (u32)f2bf(v1.z * s) | ((u32)f2bf(v1.w * s) << 16);
    ((uint4*)(hb + (size_t)row * DIM))[lane] = o;
}

// ---------------- kernel 2: per-row positive-pair count --------------------
// labels are in [0,100) for this problem; 256-bin histogram, single block
__global__ __launch_bounds__(256) void cnt_kernel(
        const int* __restrict__ labels, float* __restrict__ cnt) {
    __shared__ int hist[256];
    int tid = threadIdx.x;
    hist[tid] = 0;
    __syncthreads();
    for (int i = tid; i < N_ROWS; i += 256)
        atomicAdd(&hist[labels[i] & 255], 1);
    __syncthreads();
    for (int i = tid; i < N_ROWS; i += 256)
        cnt[i] = (float)(hist[labels[i] & 255] - 1);
}

// ---------------- kernel 3: fused tile GEMM + exp + masked row sums --------
// grid 64x64 tiles, 256 threads (4 waves, 2x2), wave tile 64x64 via 4x4 MFMA
__global__ __launch_bounds__(256) void tile_kernel(
        const u16* __restrict__ hb, const int* __restrict__ labels,
        float* __restrict__ rowTotal, float* __restrict__ rowPos) {
    __shared__ __align__(16) u16 ldsA[BM * BK];
    __shared__ __align__(16) u16 ldsB[BN * BK];
    __shared__ int labR[BM];
    __shared__ int labC[BN];

    const int bi = blockIdx.x;
    const int rowBase = (bi >> 6) * BM;
    const int colBase = (bi & 63) * BN;
    const int tid = threadIdx.x;

    if (tid < 128) labR[tid] = labels[rowBase + tid];
    else           labC[tid - 128] = labels[colBase + tid - 128];

    const int w = tid >> 6;
    const int lane = tid & 63;
    const int wm = (w >> 1) * 64;   // wave row offset in tile
    const int wn = (w & 1) * 64;    // wave col offset in tile
    const int quad = lane >> 4;
    const int l16 = lane & 15;

    f32x4 acc[4][4];
#pragma unroll
    for (int i = 0; i < 4; ++i)
#pragma unroll
        for (int j = 0; j < 4; ++j)
            acc[i][j] = (f32x4){0.f, 0.f, 0.f, 0.f};

    for (int k0 = 0; k0 < DIM; k0 += BK) {
        // stage A and B tiles: 16 B per thread per issue, contiguous in lane order
#pragma unroll
        for (int s = 0; s < 4; ++s) {
            int seg = tid + s * 256;          // 0..1023
            int r = seg >> 3;                 // 0..127
            int cs = (seg & 7) * 8;           // 0..56 (elements)
            const u16* ga = hb + (size_t)(rowBase + r) * DIM + k0 + cs;
            const u16* gb = hb + (size_t)(colBase + r) * DIM + k0 + cs;
            __builtin_amdgcn_global_load_lds(
                (const __attribute__((address_space(1))) void*)ga,
                (__attribute__((address_space(3))) void*)&ldsA[seg * 8], 16, 0, 0);
            __builtin_amdgcn_global_load_lds(
                (const __attribute__((address_space(1))) void*)gb,
                (__attribute__((address_space(3))) void*)&ldsB[seg * 8], 16, 0, 0);
        }
        __syncthreads();
#pragma unroll
        for (int kk = 0; kk < BK; kk += 32) {
            bf16x8 af[4], bfr[4];
#pragma unroll
            for (int im = 0; im < 4; ++im)
                af[im] = *(const bf16x8*)&ldsA[(wm + im * 16 + l16) * BK + kk + quad * 8];
#pragma unroll
            for (int in = 0; in < 4; ++in)
                bfr[in] = *(const bf16x8*)&ldsB[(wn + in * 16 + l16) * BK + kk + quad * 8];
#pragma unroll
            for (int im = 0; im < 4; ++im)
#pragma unroll
                for (int in = 0; in < 4; ++in)
                    acc[im][in] = __builtin_amdgcn_mfma_f32_16x16x32_bf16(
                        af[im], bfr[in], acc[im][in], 0, 0, 0);
        }
        __syncthreads();
    }

    // epilogue: exp, mask, per-row partial sums
    // C/D layout: col = l16, row = quad*4 + reg (within each 16x16 frag)
#pragma unroll
    for (int im = 0; im < 4; ++im) {
#pragma unroll
        for (int reg = 0; reg < 4; ++reg) {
            int rloc = wm + im * 16 + quad * 4 + reg;
            int gi = rowBase + rloc;
            int li = labR[rloc];
            float tsum = 0.f, psum = 0.f;
#pragma unroll
            for (int in = 0; in < 4; ++in) {
                int cloc = wn + in * 16 + l16;
                int gj = colBase + cloc;
                float e = __expf(acc[im][in][reg] * TEMP_INV);
                tsum += e;
                bool m = (labC[cloc] == li) && (gi != gj);
                psum += m ? e : 0.f;
            }
#pragma unroll
            for (int off = 1; off < 16; off <<= 1) {
                tsum += __shfl_xor(tsum, off);
                psum += __shfl_xor(psum, off);
            }
            if (l16 == 0) {
                atomicAdd(&rowTotal[gi], tsum);
                atomicAdd(&rowPos[gi], psum);
            }
        }
    }
}

// ---------------- kernel 4: final loss reduce ------------------------------
__global__ __launch_bounds__(256) void loss_kernel(
        const float* __restrict__ rowTotal, const float* __restrict__ rowPos,
        const float* __restrict__ cnt, float* __restrict__ out) {
    __shared__ double red[256];
    int tid = threadIdx.x;
    double s = 0.0;
    for (int i = tid; i < N_ROWS; i += 256) {
        float ps = rowPos[i] / (cnt[i] + 1e-9f);
        s += (double)logf(ps / rowTotal[i]);
    }
    red[tid] = s;
    __syncthreads();
    for (int st = 128; st; st >>= 1) {
        if (tid < st) red[tid] += red[tid + st];
        __syncthreads();
    }
    if (tid == 0) out[0] = (float)(-red[0] / (double)N_ROWS);
}

extern "C" void kernel_launch(void* const* d_in, const int* in_sizes, int n_in,
                              void* d_out, int out_size, void* d_ws, size_t ws_size,
                              hipStream_t stream) {
    const float* hidden = (const float*)d_in[0];
    const int* labels   = (const int*)d_in[1];
    float* out = (float*)d_out;

    char* ws = (char*)d_ws;
    u16* hb = (u16*)ws;                                     // 8192*512*2 = 8 MB
    float* rowTotal = (float*)(ws + (size_t)N_ROWS * DIM * 2);
    float* rowPos   = rowTotal + N_ROWS;
    float* cnt      = rowPos + N_ROWS;

    // zero the atomic accumulators (ws is poisoned 0xAA before every launch)
    hipMemsetAsync(rowTotal, 0, 2 * N_ROWS * sizeof(float), stream);

    norm_cast_kernel<<<N_ROWS / 4, 256, 0, stream>>>(hidden, hb);
    cnt_kernel<<<1, 256, 0, stream>>>(labels, cnt);
    tile_kernel<<<64 * 64, 256, 0, stream>>>(hb, labels, rowTotal, rowPos);
    loss_kernel<<<1, 256, 0, stream>>>(rowTotal, rowPos, cnt, out);
}

// Round 2
// 181.450 us; speedup vs baseline: 1.7524x; 1.7524x over previous
//
#include <hip/hip_runtime.h>
#include <hip/hip_bf16.h>

typedef unsigned short u16;
typedef unsigned int u32;
typedef __bf16 bf16x8 __attribute__((ext_vector_type(8)));
typedef float f32x4 __attribute__((ext_vector_type(4)));

#define N_ROWS 8192
#define DIM 512
#define BM 128
#define BN 128
#define BK 64
#define TEMP_INV (1.0f / 0.07f)

// round-to-nearest-even float -> bf16 bit pattern
__device__ __forceinline__ u16 f2bf(float f) {
    union { float f; u32 u; } a;
    a.f = f;
    u32 r = a.u + 0x7FFFu + ((a.u >> 16) & 1u);
    return (u16)(r >> 16);
}

// ---------------- kernel 1: L2-normalize rows, cast to bf16 ----------------
__global__ __launch_bounds__(256) void norm_cast_kernel(
        const float* __restrict__ x, u16* __restrict__ hb) {
    int row  = blockIdx.x * 4 + (threadIdx.x >> 6);
    int lane = threadIdx.x & 63;
    const float4* xr = (const float4*)(x + (size_t)row * DIM);
    float4 v0 = xr[lane * 2 + 0];
    float4 v1 = xr[lane * 2 + 1];
    float ss = v0.x * v0.x + v0.y * v0.y + v0.z * v0.z + v0.w * v0.w
             + v1.x * v1.x + v1.y * v1.y + v1.z * v1.z + v1.w * v1.w;
#pragma unroll
    for (int off = 32; off; off >>= 1) ss += __shfl_xor(ss, off);
    float s = 1.0f / fmaxf(sqrtf(ss), 1e-12f);
    uint4 o;
    o.x = (u32)f2bf(v0.x * s) | ((u32)f2bf(v0.y * s) << 16);
    o.y = (u32)f2bf(v0.z * s) | ((u32)f2bf(v0.w * s) << 16);
    o.z = (u32)f2bf(v1.x * s) | ((u32)f2bf(v1.y * s) << 16);
    o.w = (u32)f2bf(v1.z * s) | ((u32)f2bf(v1.w * s) << 16);
    ((uint4*)(hb + (size_t)row * DIM))[lane] = o;
}

// ---------------- kernel 2: fused tile GEMM + exp + masked COLUMN sums -----
// sim = h.h^T is symmetric and the mask is symmetric => row sums == col sums.
// Column sums reduce over (quad,reg): in-register adds + 2 shuffles only.
__global__ __launch_bounds__(256) void tile_kernel(
        const u16* __restrict__ hb, const int* __restrict__ labels,
        float* __restrict__ rowTotal, float* __restrict__ rowPos) {
    __shared__ __align__(16) u16 ldsA[BM * BK];
    __shared__ __align__(16) u16 ldsB[BN * BK];
    __shared__ int labR[BM];
    __shared__ int labC[BN];
    __shared__ float cTot[BN];
    __shared__ float cPos[BN];

    const int bi = blockIdx.x;
    const int rowBase = (bi >> 6) * BM;
    const int colBase = (bi & 63) * BN;
    const int tid = threadIdx.x;

    if (tid < 128) { labR[tid] = labels[rowBase + tid];       cTot[tid] = 0.f; }
    else           { labC[tid - 128] = labels[colBase + tid - 128]; cPos[tid - 128] = 0.f; }

    const int w = tid >> 6;
    const int lane = tid & 63;
    const int wm = (w >> 1) * 64;   // wave row offset in tile
    const int wn = (w & 1) * 64;    // wave col offset in tile
    const int quad = lane >> 4;
    const int l16 = lane & 15;
    const int sw = l16 & 7;         // xor-swizzle key (row & 7 for frag rows)

    f32x4 acc[4][4];
#pragma unroll
    for (int i = 0; i < 4; ++i)
#pragma unroll
        for (int j = 0; j < 4; ++j)
            acc[i][j] = (f32x4){0.f, 0.f, 0.f, 0.f};

    for (int k0 = 0; k0 < DIM; k0 += BK) {
        // stage tiles; 16 B chunks xor-swizzled within each 128 B row so that
        // fragment reads are bank-conflict-free. LDS dst stays lane-contiguous.
#pragma unroll
        for (int s = 0; s < 4; ++s) {
            int seg = tid + s * 256;          // 0..1023
            int r = seg >> 3;                 // 0..127
            int c8 = seg & 7;                 // chunk slot in LDS
            int gc = (k0 >> 3) + (c8 ^ (r & 7));  // source chunk in global
            const u16* ga = hb + (size_t)(rowBase + r) * DIM + gc * 8;
            const u16* gb = hb + (size_t)(colBase + r) * DIM + gc * 8;
            __builtin_amdgcn_global_load_lds(
                (const __attribute__((address_space(1))) void*)ga,
                (__attribute__((address_space(3))) void*)&ldsA[seg * 8], 16, 0, 0);
            __builtin_amdgcn_global_load_lds(
                (const __attribute__((address_space(1))) void*)gb,
                (__attribute__((address_space(3))) void*)&ldsB[seg * 8], 16, 0, 0);
        }
        __syncthreads();
#pragma unroll
        for (int kk8 = 0; kk8 < 8; kk8 += 4) {   // two K=32 steps (chunk units)
            bf16x8 af[4], bfr[4];
#pragma unroll
            for (int im = 0; im < 4; ++im)
                af[im] = *(const bf16x8*)
                    &ldsA[(wm + im * 16 + l16) * BK + (((kk8 + quad) ^ sw) * 8)];
#pragma unroll
            for (int in = 0; in < 4; ++in)
                bfr[in] = *(const bf16x8*)
                    &ldsB[(wn + in * 16 + l16) * BK + (((kk8 + quad) ^ sw) * 8)];
#pragma unroll
            for (int im = 0; im < 4; ++im)
#pragma unroll
                for (int in = 0; in < 4; ++in)
                    acc[im][in] = __builtin_amdgcn_mfma_f32_16x16x32_bf16(
                        af[im], bfr[in], acc[im][in], 0, 0, 0);
        }
        __syncthreads();
    }

    // epilogue: column sums (== row sums by symmetry)
    // C/D: col = l16, row = quad*4 + reg (within each 16x16 frag)
    int lr[4][4];
#pragma unroll
    for (int im = 0; im < 4; ++im)
#pragma unroll
        for (int reg = 0; reg < 4; ++reg)
            lr[im][reg] = labR[wm + im * 16 + quad * 4 + reg];
    const int dd = colBase - rowBase;   // diag element iff rloc - cloc == dd

#pragma unroll
    for (int in = 0; in < 4; ++in) {
        int cloc = wn + in * 16 + l16;
        int lc = labC[cloc];
        float t = 0.f, p = 0.f;
#pragma unroll
        for (int im = 0; im < 4; ++im)
#pragma unroll
            for (int reg = 0; reg < 4; ++reg) {
                int rloc = wm + im * 16 + quad * 4 + reg;
                float e = __expf(acc[im][in][reg] * TEMP_INV);
                t += e;
                bool pos = (lr[im][reg] == lc) && (rloc - cloc != dd);
                p += pos ? e : 0.f;
            }
        t += __shfl_xor(t, 16); t += __shfl_xor(t, 32);
        p += __shfl_xor(p, 16); p += __shfl_xor(p, 32);
        if (quad == 0) {
            atomicAdd(&cTot[cloc], t);
            atomicAdd(&cPos[cloc], p);
        }
    }
    __syncthreads();
    if (tid < 128) atomicAdd(&rowTotal[colBase + tid], cTot[tid]);
    else           atomicAdd(&rowPos[colBase + tid - 128], cPos[tid - 128]);
}

// ---------------- kernel 3: histogram + final loss reduce ------------------
__global__ __launch_bounds__(256) void loss_kernel(
        const int* __restrict__ labels, const float* __restrict__ rowTotal,
        const float* __restrict__ rowPos, float* __restrict__ out) {
    __shared__ int hist[128];
    __shared__ float red[256];
    int tid = threadIdx.x;
    if (tid < 128) hist[tid] = 0;
    __syncthreads();
    for (int i = tid; i < N_ROWS; i += 256)
        atomicAdd(&hist[labels[i] & 127], 1);
    __syncthreads();
    float s = 0.f;
    for (int i = blockIdx.x * 256 + tid; i < N_ROWS; i += 256 * gridDim.x) {
        float c = (float)(hist[labels[i] & 127] - 1);
        float ps = rowPos[i] / (c + 1e-9f);
        s += logf(ps / rowTotal[i]);
    }
    red[tid] = s;
    __syncthreads();
    for (int st = 128; st; st >>= 1) {
        if (tid < st) red[tid] += red[tid + st];
        __syncthreads();
    }
    if (tid == 0) atomicAdd(out, -red[0] / (float)N_ROWS);
}

extern "C" void kernel_launch(void* const* d_in, const int* in_sizes, int n_in,
                              void* d_out, int out_size, void* d_ws, size_t ws_size,
                              hipStream_t stream) {
    const float* hidden = (const float*)d_in[0];
    const int* labels   = (const int*)d_in[1];
    float* out = (float*)d_out;

    char* ws = (char*)d_ws;
    u16* hb = (u16*)ws;                                     // 8192*512*2 = 8 MB
    float* rowTotal = (float*)(ws + (size_t)N_ROWS * DIM * 2);
    float* rowPos   = rowTotal + N_ROWS;

    hipMemsetAsync(rowTotal, 0, 2 * N_ROWS * sizeof(float), stream);
    hipMemsetAsync(out, 0, sizeof(float), stream);

    norm_cast_kernel<<<N_ROWS / 4, 256, 0, stream>>>(hidden, hb);
    tile_kernel<<<64 * 64, 256, 0, stream>>>(hb, labels, rowTotal, rowPos);
    loss_kernel<<<8, 256, 0, stream>>>(labels, rowTotal, rowPos, out);
}

// Round 3
// 168.708 us; speedup vs baseline: 1.8847x; 1.0755x over previous
//
#include <hip/hip_runtime.h>
#include <hip/hip_bf16.h>

typedef unsigned short u16;
typedef unsigned int u32;
typedef __bf16 bf16x8 __attribute__((ext_vector_type(8)));
typedef float f32x4 __attribute__((ext_vector_type(4)));

#define N_ROWS 8192
#define DIM 512
#define BM 128
#define BN 128
#define BK 64
#define NT 64              // tile count per dim
#define NBLK (NT * (NT + 1) / 2)   // 2080 triangular tile pairs
#define TEMP_INV (1.0f / 0.07f)

// round-to-nearest-even float -> bf16 bit pattern
__device__ __forceinline__ u16 f2bf(float f) {
    union { float f; u32 u; } a;
    a.f = f;
    u32 r = a.u + 0x7FFFu + ((a.u >> 16) & 1u);
    return (u16)(r >> 16);
}

// ---------------- kernel 1: L2-normalize rows -> bf16; zero accumulators ---
__global__ __launch_bounds__(256) void norm_cast_kernel(
        const float* __restrict__ x, u16* __restrict__ hb,
        float* __restrict__ acc0 /* rowTotal||rowPos, 16384 floats */) {
    if (blockIdx.x < 64) acc0[blockIdx.x * 256 + threadIdx.x] = 0.f;
    int row  = blockIdx.x * 4 + (threadIdx.x >> 6);
    int lane = threadIdx.x & 63;
    const float4* xr = (const float4*)(x + (size_t)row * DIM);
    float4 v0 = xr[lane * 2 + 0];
    float4 v1 = xr[lane * 2 + 1];
    float ss = v0.x * v0.x + v0.y * v0.y + v0.z * v0.z + v0.w * v0.w
             + v1.x * v1.x + v1.y * v1.y + v1.z * v1.z + v1.w * v1.w;
#pragma unroll
    for (int off = 32; off; off >>= 1) ss += __shfl_xor(ss, off);
    float s = 1.0f / fmaxf(sqrtf(ss), 1e-12f);
    uint4 o;
    o.x = (u32)f2bf(v0.x * s) | ((u32)f2bf(v0.y * s) << 16);
    o.y = (u32)f2bf(v0.z * s) | ((u32)f2bf(v0.w * s) << 16);
    o.z = (u32)f2bf(v1.x * s) | ((u32)f2bf(v1.y * s) << 16);
    o.w = (u32)f2bf(v1.z * s) | ((u32)f2bf(v1.w * s) << 16);
    ((uint4*)(hb + (size_t)row * DIM))[lane] = o;
}

// ---------------- kernel 2: triangular fused tile GEMM + exp + sums --------
// sim is symmetric: only tiles ti<=tj are computed. Off-diagonal tiles emit
// column sums (-> rows of tj) AND row sums (-> rows of ti, via e(i,j)=e(j,i)).
// Diagonal tiles emit column sums only (full 128x128 computed once).
__global__ __launch_bounds__(256) void tile_kernel(
        const u16* __restrict__ hb, const int* __restrict__ labels,
        float* __restrict__ rowTotal, float* __restrict__ rowPos) {
    __shared__ __align__(16) u16 ldsA[BM * BK];
    __shared__ __align__(16) u16 ldsB[BN * BK];
    __shared__ int labR[BM];
    __shared__ int labC[BN];
    __shared__ float cT[2][BN], cP[2][BN];   // per wave-row column sums
    __shared__ float rT[2][BM], rP[2][BM];   // per wave-col row sums

    // decode triangular block index -> (ti, tj), ti <= tj
    const int idx = blockIdx.x;
    int ti = (int)((129.0f - sqrtf(16641.0f - 8.0f * (float)idx)) * 0.5f);
    while ((ti + 1) * (129 - (ti + 1)) / 2 <= idx) ++ti;
    while (ti * (129 - ti) / 2 > idx) --ti;
    const int tj = ti + (idx - ti * (129 - ti) / 2);
    const int rowBase = ti * BM;
    const int colBase = tj * BN;
    const bool isDiag = (ti == tj);
    const int dd = colBase - rowBase;   // diag element iff rloc - cloc == dd
    const int tid = threadIdx.x;

    if (tid < 128) labR[tid] = labels[rowBase + tid];
    else           labC[tid - 128] = labels[colBase + tid - 128];

    const int w = tid >> 6;
    const int lane = tid & 63;
    const int wm = (w >> 1) * 64;   // wave row offset in tile
    const int wn = (w & 1) * 64;    // wave col offset in tile
    const int wr = w >> 1;          // wave-row id (for cT/cP slot)
    const int wc = w & 1;           // wave-col id (for rT/rP slot)
    const int quad = lane >> 4;
    const int l16 = lane & 15;
    const int sw = l16 & 7;         // xor-swizzle key

    f32x4 acc[4][4];
#pragma unroll
    for (int i = 0; i < 4; ++i)
#pragma unroll
        for (int j = 0; j < 4; ++j)
            acc[i][j] = (f32x4){0.f, 0.f, 0.f, 0.f};

    for (int k0 = 0; k0 < DIM; k0 += BK) {
        // stage tiles; 16 B chunks xor-swizzled within each 128 B row
#pragma unroll
        for (int s = 0; s < 4; ++s) {
            int seg = tid + s * 256;          // 0..1023
            int r = seg >> 3;                 // 0..127
            int c8 = seg & 7;                 // chunk slot in LDS
            int gc = (k0 >> 3) + (c8 ^ (r & 7));
            const u16* ga = hb + (size_t)(rowBase + r) * DIM + gc * 8;
            const u16* gb = hb + (size_t)(colBase + r) * DIM + gc * 8;
            __builtin_amdgcn_global_load_lds(
                (const __attribute__((address_space(1))) void*)ga,
                (__attribute__((address_space(3))) void*)&ldsA[seg * 8], 16, 0, 0);
            __builtin_amdgcn_global_load_lds(
                (const __attribute__((address_space(1))) void*)gb,
                (__attribute__((address_space(3))) void*)&ldsB[seg * 8], 16, 0, 0);
        }
        __syncthreads();
#pragma unroll
        for (int kk8 = 0; kk8 < 8; kk8 += 4) {   // two K=32 steps
            bf16x8 af[4], bfr[4];
#pragma unroll
            for (int im = 0; im < 4; ++im)
                af[im] = *(const bf16x8*)
                    &ldsA[(wm + im * 16 + l16) * BK + (((kk8 + quad) ^ sw) * 8)];
#pragma unroll
            for (int in = 0; in < 4; ++in)
                bfr[in] = *(const bf16x8*)
                    &ldsB[(wn + in * 16 + l16) * BK + (((kk8 + quad) ^ sw) * 8)];
#pragma unroll
            for (int im = 0; im < 4; ++im)
#pragma unroll
                for (int in = 0; in < 4; ++in)
                    acc[im][in] = __builtin_amdgcn_mfma_f32_16x16x32_bf16(
                        af[im], bfr[in], acc[im][in], 0, 0, 0);
        }
        __syncthreads();
    }

    // ---------------- epilogue ----------------
    // C/D layout: col = l16, row = quad*4 + reg (within each 16x16 frag)
    int lc[4];
#pragma unroll
    for (int in = 0; in < 4; ++in) lc[in] = labC[wn + in * 16 + l16];

    float colT[4] = {0.f, 0.f, 0.f, 0.f}, colP[4] = {0.f, 0.f, 0.f, 0.f};
#pragma unroll
    for (int im = 0; im < 4; ++im) {
        float rowT[4] = {0.f, 0.f, 0.f, 0.f}, rowP[4] = {0.f, 0.f, 0.f, 0.f};
#pragma unroll
        for (int reg = 0; reg < 4; ++reg) {
            int rloc = wm + im * 16 + quad * 4 + reg;
            int li = labR[rloc];
#pragma unroll
            for (int in = 0; in < 4; ++in) {
                int cloc = wn + in * 16 + l16;
                float e = __expf(acc[im][in][reg] * TEMP_INV);
                bool pos = (lc[in] == li) && (rloc - cloc != dd);
                colT[in] += e; rowT[reg] += e;
                if (pos) { colP[in] += e; rowP[reg] += e; }
            }
        }
        if (!isDiag) {
            // reduce rowT/rowP over the 16 l16 lanes
#pragma unroll
            for (int reg = 0; reg < 4; ++reg) {
                float t = rowT[reg], p = rowP[reg];
                t += __shfl_xor(t, 1); t += __shfl_xor(t, 2);
                t += __shfl_xor(t, 4); t += __shfl_xor(t, 8);
                p += __shfl_xor(p, 1); p += __shfl_xor(p, 2);
                p += __shfl_xor(p, 4); p += __shfl_xor(p, 8);
                if (l16 == 0) {
                    int rloc = wm + im * 16 + quad * 4 + reg;
                    rT[wc][rloc] = t;   // distinct rloc per (im,quad,reg); full 64-row cover
                    rP[wc][rloc] = p;
                }
            }
        }
    }
    // reduce colT/colP over quads
#pragma unroll
    for (int in = 0; in < 4; ++in) {
        float t = colT[in], p = colP[in];
        t += __shfl_xor(t, 16); t += __shfl_xor(t, 32);
        p += __shfl_xor(p, 16); p += __shfl_xor(p, 32);
        if (quad == 0) {
            int cloc = wn + in * 16 + l16;
            cT[wr][cloc] = t;
            cP[wr][cloc] = p;
        }
    }
    __syncthreads();
    if (tid < 128) {
        atomicAdd(&rowTotal[colBase + tid], cT[0][tid] + cT[1][tid]);
        if (!isDiag) atomicAdd(&rowTotal[rowBase + tid], rT[0][tid] + rT[1][tid]);
    } else {
        int t2 = tid - 128;
        atomicAdd(&rowPos[colBase + t2], cP[0][t2] + cP[1][t2]);
        if (!isDiag) atomicAdd(&rowPos[rowBase + t2], rP[0][t2] + rP[1][t2]);
    }
}

// ---------------- kernel 3: histogram + final loss reduce (1 block) --------
__global__ __launch_bounds__(256) void loss_kernel(
        const int* __restrict__ labels, const float* __restrict__ rowTotal,
        const float* __restrict__ rowPos, float* __restrict__ out) {
    __shared__ int hist[128];
    __shared__ float red[256];
    int tid = threadIdx.x;
    if (tid < 128) hist[tid] = 0;
    __syncthreads();
    for (int i = tid; i < N_ROWS; i += 256)
        atomicAdd(&hist[labels[i] & 127], 1);
    __syncthreads();
    float s = 0.f;
    for (int i = tid; i < N_ROWS; i += 256) {
        float c = (float)(hist[labels[i] & 127] - 1);
        float ps = rowPos[i] / (c + 1e-9f);
        s += logf(ps / rowTotal[i]);
    }
    red[tid] = s;
    __syncthreads();
    for (int st = 128; st; st >>= 1) {
        if (tid < st) red[tid] += red[tid + st];
        __syncthreads();
    }
    if (tid == 0) out[0] = -red[0] / (float)N_ROWS;
}

extern "C" void kernel_launch(void* const* d_in, const int* in_sizes, int n_in,
                              void* d_out, int out_size, void* d_ws, size_t ws_size,
                              hipStream_t stream) {
    const float* hidden = (const float*)d_in[0];
    const int* labels   = (const int*)d_in[1];
    float* out = (float*)d_out;

    char* ws = (char*)d_ws;
    u16* hb = (u16*)ws;                                     // 8192*512*2 = 8 MB
    float* rowTotal = (float*)(ws + (size_t)N_ROWS * DIM * 2);
    float* rowPos   = rowTotal + N_ROWS;

    norm_cast_kernel<<<N_ROWS / 4, 256, 0, stream>>>(hidden, hb, rowTotal);
    tile_kernel<<<NBLK, 256, 0, stream>>>(hb, labels, rowTotal, rowPos);
    loss_kernel<<<1, 256, 0, stream>>>(labels, rowTotal, rowPos, out);
}